// Round 1
// baseline (796.488 us; speedup 1.0000x reference)
//
#include <hip/hip_runtime.h>
#include <hip/hip_bf16.h>

#define NNODES 20000
#define NEDGES 640000
#define NB 50
#define NF 128
#define NBLK_SCAN 79   // ceil(20000/256)
#define NTILES (NEDGES / 16)   // 40000 exact

typedef unsigned int uint_t;
typedef unsigned short ushort_t;

typedef __bf16 bf16x8 __attribute__((ext_vector_type(8)));
typedef float f32x4 __attribute__((ext_vector_type(4)));

// fast shifted softplus: hardware v_exp_f32 / v_log_f32
__device__ __forceinline__ float ssp_f(float x) {
    float t = __expf(-fabsf(x));
    return fmaxf(x, 0.0f) + __logf(1.0f + t) - 0.6931471805599453f;
}

__device__ __forceinline__ uint_t pack2bf(float a, float b) {
    union { __bf16 h[2]; uint_t u; } t;
    t.h[0] = (__bf16)a; t.h[1] = (__bf16)b;
    return t.u;
}

// ---------------- zero hist + cnt ----------------
__global__ __launch_bounds__(256) void k_zero_small(int* __restrict__ p, int n) {
    int i = blockIdx.x * 256 + threadIdx.x;
    if (i < n) p[i] = 0;
}

// ---------------- histogram of dst ----------------
__global__ __launch_bounds__(256) void k_hist(const int* __restrict__ dst, int* __restrict__ hist) {
    int i = blockIdx.x * 256 + threadIdx.x;
    if (i < NEDGES) atomicAdd(&hist[dst[i]], 1);
}

// ---------------- hierarchical exclusive scan: blocksums ----------------
__global__ __launch_bounds__(256) void k_bsum(const int* __restrict__ hist, int* __restrict__ bsum) {
    __shared__ int ws[4];
    int i = blockIdx.x * 256 + threadIdx.x;
    int v = (i < NNODES) ? hist[i] : 0;
    #pragma unroll
    for (int s = 1; s < 64; s <<= 1) v += __shfl_xor(v, s, 64);
    if ((threadIdx.x & 63) == 0) ws[threadIdx.x >> 6] = v;
    __syncthreads();
    if (threadIdx.x == 0) bsum[blockIdx.x] = ws[0] + ws[1] + ws[2] + ws[3];
}

__global__ __launch_bounds__(64) void k_scan_b(const int* __restrict__ bsum, int* __restrict__ bbase) {
    if (threadIdx.x == 0) {
        int acc = 0;
        for (int b = 0; b < NBLK_SCAN; ++b) { bbase[b] = acc; acc += bsum[b]; }
    }
}

__global__ __launch_bounds__(256) void k_off(const int* __restrict__ hist, const int* __restrict__ bbase,
                                             int* __restrict__ off) {
    __shared__ int buf[256];
    int i = blockIdx.x * 256 + threadIdx.x;
    int v = (i < NNODES) ? hist[i] : 0;
    buf[threadIdx.x] = v;
    __syncthreads();
    #pragma unroll
    for (int s = 1; s < 256; s <<= 1) {
        int t = (threadIdx.x >= (unsigned)s) ? buf[threadIdx.x - s] : 0;
        __syncthreads();
        buf[threadIdx.x] += t;
        __syncthreads();
    }
    if (i < NNODES) off[i] = bbase[blockIdx.x] + buf[threadIdx.x] - v;
    if (i == NNODES) off[NNODES] = NEDGES;
}

// ---------------- scatter: dst-grouped perm + pre-gathered src ----------------
__global__ __launch_bounds__(256) void k_scatter(const int* __restrict__ src, const int* __restrict__ dst,
                                                 const int* __restrict__ off, int* __restrict__ cnt,
                                                 int* __restrict__ perm, int* __restrict__ srcs) {
    int i = blockIdx.x * 256 + threadIdx.x;
    if (i < NEDGES) {
        int d = dst[i];
        int pos = off[d] + atomicAdd(&cnt[d], 1);
        perm[pos] = i;
        srcs[pos] = src[i];
    }
}

// ---------------- node GEMM: Y = X @ W  (MFMA, 64-row tile) ----------------
// Output written in PACKED PAIR layout: f32 word-pair w = p*16+c holds
// columns (p*32+c, p*32+16+c) as a float2 at byte offset row*512 + w*8.
__global__ __launch_bounds__(256) void k_node1(const float* __restrict__ X,
                                               const float* __restrict__ W,
                                               float* __restrict__ Y, int nrows)
{
    __shared__ alignas(16) __bf16 sx[64 * 136];
    const int tid  = threadIdx.x;
    const int wv   = tid >> 6, lane = tid & 63;
    const int col  = lane & 15, quad = lane >> 4;

    bf16x8 wf[2][4];
    #pragma unroll
    for (int nt = 0; nt < 2; ++nt) {
        int n = wv * 32 + nt * 16 + col;
        #pragma unroll
        for (int kc = 0; kc < 4; ++kc)
            #pragma unroll
            for (int j = 0; j < 8; ++j)
                wf[nt][kc][j] = (__bf16)W[(kc * 32 + quad * 8 + j) * NF + n];
    }

    const int rbase = blockIdx.x * 64;
    for (int i = tid; i < 64 * 64; i += 256) {
        int r = i >> 6, c = i & 63;
        int gr = rbase + r;
        float2 v = (gr < nrows) ? *reinterpret_cast<const float2*>(&X[(size_t)gr * NF + 2 * c])
                                : make_float2(0.f, 0.f);
        sx[r * 136 + 2 * c]     = (__bf16)v.x;
        sx[r * 136 + 2 * c + 1] = (__bf16)v.y;
    }
    __syncthreads();

    f32x4 acc[4][2] = {};
    #pragma unroll
    for (int kc = 0; kc < 4; ++kc) {
        bf16x8 af[4];
        #pragma unroll
        for (int mt = 0; mt < 4; ++mt)
            af[mt] = *reinterpret_cast<const bf16x8*>(&sx[(mt * 16 + col) * 136 + kc * 32 + quad * 8]);
        #pragma unroll
        for (int mt = 0; mt < 4; ++mt)
            #pragma unroll
            for (int nt = 0; nt < 2; ++nt)
                acc[mt][nt] = __builtin_amdgcn_mfma_f32_16x16x32_bf16(af[mt], wf[nt][kc], acc[mt][nt], 0, 0, 0);
    }
    // packed-pair store: lane holds cols (wv*32+col, wv*32+16+col) = pair word wv*16+col
    #pragma unroll
    for (int mt = 0; mt < 4; ++mt)
        #pragma unroll
        for (int r = 0; r < 4; ++r) {
            int row = rbase + mt * 16 + quad * 4 + r;
            if (row < nrows)
                *reinterpret_cast<float2*>(&Y[(size_t)row * NF + (size_t)(wv * 16 + col) * 2]) =
                    make_float2(acc[mt][0][r], acc[mt][1][r]);
        }
}

// ---------------- fused tail: out = ssp(X @ W1 + b1) @ W2 + b2 ----------------
// X (agg) arrives in PACKED PAIR layout; staging unpacks it.
__global__ __launch_bounds__(256) void k_tail(const float* __restrict__ X,
                                              const float* __restrict__ W1, const float* __restrict__ B1,
                                              const float* __restrict__ W2, const float* __restrict__ B2,
                                              float* __restrict__ Y, int nrows)
{
    __shared__ alignas(16) __bf16 sx[64 * 136];
    __shared__ alignas(16) __bf16 st[64 * 136];
    const int tid  = threadIdx.x;
    const int wv   = tid >> 6, lane = tid & 63;
    const int col  = lane & 15, quad = lane >> 4;

    bf16x8 wf1[2][4], wf2[2][4];
    float rb1[2], rb2[2];
    #pragma unroll
    for (int nt = 0; nt < 2; ++nt) {
        int n = wv * 32 + nt * 16 + col;
        rb1[nt] = B1[n]; rb2[nt] = B2[n];
        #pragma unroll
        for (int kc = 0; kc < 4; ++kc)
            #pragma unroll
            for (int j = 0; j < 8; ++j) {
                int k = kc * 32 + quad * 8 + j;
                wf1[nt][kc][j] = (__bf16)W1[k * NF + n];
                wf2[nt][kc][j] = (__bf16)W2[k * NF + n];
            }
    }

    const int rbase = blockIdx.x * 64;
    for (int i = tid; i < 64 * 64; i += 256) {
        int r = i >> 6, c = i & 63;
        int gr = rbase + r;
        float2 v = (gr < nrows) ? *reinterpret_cast<const float2*>(&X[(size_t)gr * NF + 2 * c])
                                : make_float2(0.f, 0.f);
        int pp = c >> 4, cw = c & 15;   // word c = cols (pp*32+cw, pp*32+16+cw)
        sx[r * 136 + pp * 32 + cw]      = (__bf16)v.x;
        sx[r * 136 + pp * 32 + 16 + cw] = (__bf16)v.y;
    }
    __syncthreads();

    f32x4 acc[4][2];
    #pragma unroll
    for (int mt = 0; mt < 4; ++mt)
        #pragma unroll
        for (int nt = 0; nt < 2; ++nt)
            acc[mt][nt] = f32x4{rb1[nt], rb1[nt], rb1[nt], rb1[nt]};
    #pragma unroll
    for (int kc = 0; kc < 4; ++kc) {
        bf16x8 af[4];
        #pragma unroll
        for (int mt = 0; mt < 4; ++mt)
            af[mt] = *reinterpret_cast<const bf16x8*>(&sx[(mt * 16 + col) * 136 + kc * 32 + quad * 8]);
        #pragma unroll
        for (int mt = 0; mt < 4; ++mt)
            #pragma unroll
            for (int nt = 0; nt < 2; ++nt)
                acc[mt][nt] = __builtin_amdgcn_mfma_f32_16x16x32_bf16(af[mt], wf1[nt][kc], acc[mt][nt], 0, 0, 0);
    }
    #pragma unroll
    for (int mt = 0; mt < 4; ++mt)
        #pragma unroll
        for (int nt = 0; nt < 2; ++nt)
            #pragma unroll
            for (int r = 0; r < 4; ++r)
                st[(mt * 16 + quad * 4 + r) * 136 + wv * 32 + nt * 16 + col] = (__bf16)ssp_f(acc[mt][nt][r]);
    __syncthreads();

    f32x4 acc2[4][2];
    #pragma unroll
    for (int mt = 0; mt < 4; ++mt)
        #pragma unroll
        for (int nt = 0; nt < 2; ++nt)
            acc2[mt][nt] = f32x4{rb2[nt], rb2[nt], rb2[nt], rb2[nt]};
    #pragma unroll
    for (int kc = 0; kc < 4; ++kc) {
        bf16x8 af[4];
        #pragma unroll
        for (int mt = 0; mt < 4; ++mt)
            af[mt] = *reinterpret_cast<const bf16x8*>(&st[(mt * 16 + col) * 136 + kc * 32 + quad * 8]);
        #pragma unroll
        for (int mt = 0; mt < 4; ++mt)
            #pragma unroll
            for (int nt = 0; nt < 2; ++nt)
                acc2[mt][nt] = __builtin_amdgcn_mfma_f32_16x16x32_bf16(af[mt], wf2[nt][kc], acc2[mt][nt], 0, 0, 0);
    }
    #pragma unroll
    for (int mt = 0; mt < 4; ++mt)
        #pragma unroll
        for (int nt = 0; nt < 2; ++nt)
            #pragma unroll
            for (int r = 0; r < 4; ++r) {
                int row = rbase + mt * 16 + quad * 4 + r;
                if (row < nrows) Y[(size_t)row * NF + wv * 32 + nt * 16 + col] = acc2[mt][nt][r];
            }
}

// ---------------- dense edge-filter MLP: msg[e] = bf16( (ssp(ea@w1+b1)@w2+b2) * C ) ----------------
// Edges processed in ORIGINAL order (fully coalesced). 6 waves/block share
// weight LDS (63 KB total -> 2 blocks/CU = 12 waves/CU). Each wave owns one
// 16-edge MFMA tile per iteration; no gathers, no segment walk.
// msg packed layout: u32 word w = p*16+c holds bf16 cols (p*32+c, p*32+16+c).
__global__ __launch_bounds__(384, 3) void k_filter(
    const float* __restrict__ ea, const float* __restrict__ ew,
    const float* __restrict__ w1, const float* __restrict__ b1,
    const float* __restrict__ w2, const float* __restrict__ b2,
    uint_t* __restrict__ msg)
{
    __shared__ alignas(16) __bf16 w1f[16 * 64 * 8];   // 16 KB, frag = ntg*2+kc
    __shared__ alignas(16) __bf16 w2f[32 * 64 * 8];   // 32 KB, frag = ntg*4+kc
    __shared__ alignas(16) __bf16 st1[6][16 * 72];    // 13.5 KB, wave-private halves

    const int tid  = threadIdx.x;
    const int wv   = tid >> 6, lane = tid & 63;
    const int col  = lane & 15, quad = lane >> 4;

    for (int idx = tid; idx < 16 * 64; idx += 384) {
        int fr = idx >> 6, l = idx & 63;
        int ntg = fr >> 1, kc = fr & 1;
        int n = ntg * 16 + (l & 15), kb = kc * 32 + (l >> 4) * 8;
        __bf16* d = &w1f[idx * 8];
        #pragma unroll
        for (int j = 0; j < 8; ++j) {
            int k = kb + j;
            d[j] = (__bf16)((k < NB) ? w1[k * NF + n] : 0.0f);
        }
    }
    for (int idx = tid; idx < 32 * 64; idx += 384) {
        int fr = idx >> 6, l = idx & 63;
        int ntg = fr >> 2, kc = fr & 3;
        int n = ntg * 16 + (l & 15), kb = kc * 32 + (l >> 4) * 8;
        __bf16* d = &w2f[idx * 8];
        #pragma unroll
        for (int j = 0; j < 8; ++j)
            d[j] = (__bf16)w2[(kb + j) * NF + n];
    }
    float rb1[8], rb2[8];
    #pragma unroll
    for (int nt = 0; nt < 8; ++nt) { rb1[nt] = b1[nt * 16 + col]; rb2[nt] = b2[nt * 16 + col]; }
    __syncthreads();   // the only barrier

    __bf16* myst = st1[wv];

    for (int tile = blockIdx.x * 6 + wv; tile < NTILES; tile += gridDim.x * 6) {
        const int base = tile * 16;

        // A-frags from ea rows (row = col), coalesced contiguous 16-row block
        const float* erow = ea + (size_t)(base + col) * NB;
        bf16x8 af0, af1;
        #pragma unroll
        for (int p = 0; p < 4; ++p) {
            float2 v = *reinterpret_cast<const float2*>(erow + quad * 8 + 2 * p);
            af0[2 * p]     = (__bf16)v.x;
            af0[2 * p + 1] = (__bf16)v.y;
        }
        #pragma unroll
        for (int p = 0; p < 4; ++p) {
            int k = 32 + quad * 8 + 2 * p;
            float2 v = (k + 2 <= NB) ? *reinterpret_cast<const float2*>(erow + k)
                                     : make_float2(0.f, 0.f);
            af1[2 * p]     = (__bf16)v.x;
            af1[2 * p + 1] = (__bf16)v.y;
        }

        // cosine cutoff per edge; per-output-row copy via shfl
        float Cv = 0.5f * (__cosf(ew[base + col] * 0.31415926535897931f) + 1.0f);
        float Cw[4];
        #pragma unroll
        for (int r = 0; r < 4; ++r) Cw[r] = __shfl(Cv, quad * 4 + r, 64);

        f32x4 acc2[8];
        #pragma unroll
        for (int nt = 0; nt < 8; ++nt) acc2[nt] = f32x4{rb2[nt], rb2[nt], rb2[nt], rb2[nt]};

        #pragma unroll
        for (int hf = 0; hf < 2; ++hf) {
            f32x4 acc1[4];
            #pragma unroll
            for (int nt = 0; nt < 4; ++nt) {
                int ntg = hf * 4 + nt;
                acc1[nt] = f32x4{rb1[ntg], rb1[ntg], rb1[ntg], rb1[ntg]};
                bf16x8 bw0 = *reinterpret_cast<const bf16x8*>(&w1f[((ntg * 2 + 0) * 64 + lane) * 8]);
                bf16x8 bw1 = *reinterpret_cast<const bf16x8*>(&w1f[((ntg * 2 + 1) * 64 + lane) * 8]);
                acc1[nt] = __builtin_amdgcn_mfma_f32_16x16x32_bf16(af0, bw0, acc1[nt], 0, 0, 0);
                acc1[nt] = __builtin_amdgcn_mfma_f32_16x16x32_bf16(af1, bw1, acc1[nt], 0, 0, 0);
            }
            #pragma unroll
            for (int nt = 0; nt < 4; ++nt)
                #pragma unroll
                for (int r = 0; r < 4; ++r)
                    myst[(quad * 4 + r) * 72 + nt * 16 + col] = (__bf16)ssp_f(acc1[nt][r]);
            bf16x8 a20 = *reinterpret_cast<const bf16x8*>(&myst[col * 72 + 0 * 32 + quad * 8]);
            bf16x8 a21 = *reinterpret_cast<const bf16x8*>(&myst[col * 72 + 1 * 32 + quad * 8]);
            #pragma unroll
            for (int nt = 0; nt < 8; ++nt) {
                bf16x8 b20 = *reinterpret_cast<const bf16x8*>(&w2f[((nt * 4 + hf * 2 + 0) * 64 + lane) * 8]);
                bf16x8 b21 = *reinterpret_cast<const bf16x8*>(&w2f[((nt * 4 + hf * 2 + 1) * 64 + lane) * 8]);
                acc2[nt] = __builtin_amdgcn_mfma_f32_16x16x32_bf16(a20, b20, acc2[nt], 0, 0, 0);
                acc2[nt] = __builtin_amdgcn_mfma_f32_16x16x32_bf16(a21, b21, acc2[nt], 0, 0, 0);
            }
        }

        // packed bf16-pair store: pair (nt=2p, nt=2p+1) -> word p*16+col
        #pragma unroll
        for (int p = 0; p < 4; ++p)
            #pragma unroll
            for (int r = 0; r < 4; ++r) {
                uint_t u = pack2bf(acc2[2 * p][r] * Cw[r], acc2[2 * p + 1][r] * Cw[r]);
                msg[(size_t)(base + quad * 4 + r) * 64 + p * 16 + col] = u;
            }
    }
}

// ---------------- streaming segment reduce: agg[n] = sum_{pos in seg(n)} msg[perm[pos]] * h[srcs[pos]] ----------------
// One wave per node; lane owns one packed word (2 columns). All loads coalesced
// (256 B msg row / 512 B h row per wave). Tiny regs -> high occupancy, pure TLP.
__global__ __launch_bounds__(256) void k_reduce(
    const int* __restrict__ off, const int* __restrict__ perm, const int* __restrict__ srcs,
    const uint_t* __restrict__ msg, const float* __restrict__ hp, float* __restrict__ agg)
{
    const int wv = threadIdx.x >> 6, lane = threadIdx.x & 63;
    for (int n = blockIdx.x * 4 + wv; n < NNODES; n += gridDim.x * 4) {
        const int s = off[n], e = off[n + 1];
        float ax = 0.f, ay = 0.f;
        int pos = s;
        for (; pos + 2 <= e; pos += 2) {
            int e0 = perm[pos],     s0 = srcs[pos];
            int e1 = perm[pos + 1], s1 = srcs[pos + 1];
            uint_t w0 = msg[(size_t)e0 * 64 + lane];
            float2 h0 = *reinterpret_cast<const float2*>(&hp[(size_t)s0 * NF + 2 * lane]);
            uint_t w1v = msg[(size_t)e1 * 64 + lane];
            float2 h1 = *reinterpret_cast<const float2*>(&hp[(size_t)s1 * NF + 2 * lane]);
            union { uint_t u; __bf16 h[2]; } t0, t1;
            t0.u = w0; t1.u = w1v;
            ax = fmaf((float)t0.h[0], h0.x, ax);
            ay = fmaf((float)t0.h[1], h0.y, ay);
            ax = fmaf((float)t1.h[0], h1.x, ax);
            ay = fmaf((float)t1.h[1], h1.y, ay);
        }
        if (pos < e) {
            int e0 = perm[pos], s0 = srcs[pos];
            uint_t w0 = msg[(size_t)e0 * 64 + lane];
            float2 h0 = *reinterpret_cast<const float2*>(&hp[(size_t)s0 * NF + 2 * lane]);
            union { uint_t u; __bf16 h[2]; } t0;
            t0.u = w0;
            ax = fmaf((float)t0.h[0], h0.x, ax);
            ay = fmaf((float)t0.h[1], h0.y, ay);
        }
        *reinterpret_cast<float2*>(&agg[(size_t)n * NF + 2 * lane]) = make_float2(ax, ay);
    }
}

extern "C" void kernel_launch(void* const* d_in, const int* in_sizes, int n_in,
                              void* d_out, int out_size, void* d_ws, size_t ws_size,
                              hipStream_t stream) {
    const float* x    = (const float*)d_in[0];
    const int*   eidx = (const int*)d_in[1];
    const float* ew   = (const float*)d_in[2];
    const float* ea   = (const float*)d_in[3];
    const float* w1   = (const float*)d_in[4];
    const float* b1   = (const float*)d_in[5];
    const float* w2   = (const float*)d_in[6];
    const float* b2   = (const float*)d_in[7];
    const float* l1w  = (const float*)d_in[8];
    const float* l2w  = (const float*)d_in[9];
    const float* l2b  = (const float*)d_in[10];
    const float* lw   = (const float*)d_in[11];
    const float* lb   = (const float*)d_in[12];
    (void)in_sizes; (void)n_in; (void)out_size; (void)ws_size;

    const int* esrc = eidx;
    const int* edst = eidx + NEDGES;

    char* p = (char*)d_ws;
    float*  hp   = (float*)p;  p += (size_t)NNODES * NF * 4;      // 10.24 MB (packed-pair h)
    float*  agg  = (float*)p;  p += (size_t)NNODES * NF * 4;      // 10.24 MB (packed-pair agg)
    int*    off  = (int*)p;    p += (size_t)(NNODES + 4) * 4;
    int*    hist = (int*)p;    p += (size_t)NNODES * 4;
    int*    cnt  = (int*)p;    p += (size_t)NNODES * 4;
    int*    bsum = (int*)p;    p += 128 * 4;
    int*    bbase= (int*)p;    p += 128 * 4;
    int*    perm = (int*)p;    p += (size_t)NEDGES * 4;           // 2.56 MB
    int*    srcs = (int*)p;    p += (size_t)NEDGES * 4;           // 2.56 MB
    uint_t* msg  = (uint_t*)p; p += (size_t)NEDGES * 64 * 4;      // 163.84 MB (bf16-pair filter output)

    // h = x @ lin1_w (MFMA), packed-pair layout
    hipLaunchKernelGGL(k_node1, dim3(313), dim3(256), 0, stream, x, l1w, hp, NNODES);

    // dst-sorted CSR build (hist -> hierarchical scan -> scatter)
    hipLaunchKernelGGL(k_zero_small, dim3(157), dim3(256), 0, stream, hist, 2 * NNODES); // hist+cnt adjacent
    hipLaunchKernelGGL(k_hist, dim3(2500), dim3(256), 0, stream, edst, hist);
    hipLaunchKernelGGL(k_bsum, dim3(NBLK_SCAN), dim3(256), 0, stream, hist, bsum);
    hipLaunchKernelGGL(k_scan_b, dim3(1), dim3(64), 0, stream, bsum, bbase);
    hipLaunchKernelGGL(k_off, dim3(NBLK_SCAN), dim3(256), 0, stream, hist, bbase, off);
    hipLaunchKernelGGL(k_scatter, dim3(2500), dim3(256), 0, stream,
                       esrc, edst, off, cnt, perm, srcs);

    // dense edge-filter MLP (original order, coalesced) -> msg
    hipLaunchKernelGGL(k_filter, dim3(500), dim3(384), 0, stream,
                       ea, ew, w1, b1, w2, b2, msg);

    // streaming per-node segment reduce -> agg (packed-pair)
    hipLaunchKernelGGL(k_reduce, dim3(2500), dim3(256), 0, stream,
                       off, perm, srcs, msg, hp, agg);

    // out = ssp(agg @ lin2_w + lin2_b) @ lin_w + lin_b (fused MFMA)
    hipLaunchKernelGGL(k_tail, dim3(313), dim3(256), 0, stream,
                       agg, l2w, l2b, lw, lb, (float*)d_out, NNODES);
}